// Round 6
// baseline (217.303 us; speedup 1.0000x reference)
//
#include <hip/hip_runtime.h>

typedef __bf16 bf16x8_t __attribute__((ext_vector_type(8)));
typedef float f32x16_t __attribute__((ext_vector_type(16)));
typedef unsigned short ushort_t;

__device__ __forceinline__ unsigned short f2bf(float f) {
  unsigned u = __float_as_uint(f);
  u = (u + 0x7FFFu + ((u >> 16) & 1u)) >> 16;
  return (unsigned short)u;
}
__device__ __forceinline__ float bf2f(unsigned short h) {
  return __uint_as_float(((unsigned)h) << 16);
}

// async global->LDS, 16B/lane. LDS dest = wave-uniform base + lane*16.
__device__ __forceinline__ void gload16(const void* g, void* l) {
  __builtin_amdgcn_global_load_lds(
      (const __attribute__((address_space(1))) unsigned int*)g,
      (__attribute__((address_space(3))) unsigned int*)l, 16, 0, 0);
}

// ===========================================================================
// 128x128 NT GEMM on mfma_f32_32x32x16_bf16 (half the MFMA instrs of 16x16x32,
// 2495 vs 2075 TF ceiling). m97-proven loop: 1 __syncthreads per K-tile,
// gload_lds dbuf staging, 4 blocks/CU TLP hides barrier stalls.
// BK=32 (64B rows = 4 x 16B chunks). Swizzle: LDS(row,chunk)=G(row,chunk^(row&3)),
// ds_read XORs the same (both-sides rule).
// 4 waves (2x2), wave = 64x64 out = 2x2 frags of 32x32, acc = 4 x f32x16.
// A/B frag: row=lane&31, k-half=lane>>5.  C/D: col=lane&31,
// row=(reg&3)+8*(reg>>2)+4*(lane>>5)  [m74/m101].
// ===========================================================================
template<bool OUT_BF16, bool HAS_BIAS>
__global__ __launch_bounds__(256, 4)
void gemm32(const ushort_t* __restrict__ A, const ushort_t* __restrict__ Bt,
            void* __restrict__ Cp, const float* __restrict__ bias,
            int gx, int gy, int K, int lda, int ldb, int ldc,
            long sA, long sB, long sC, float alpha)
{
  __shared__ __align__(16) ushort_t sm[16384];  // 2 buf x (A 4096 + B 4096)
  const int tid = threadIdx.x;
  const int lane = tid & 63;
  const int w = tid >> 6;                 // wave 0..3
  const int wr = w >> 1, wc = w & 1;

  // bijective XCD-chunked swizzle (all grids %8==0)
  const int per = gridDim.x >> 3;
  int wg = blockIdx.x;
  wg = (wg & 7) * per + (wg >> 3);
  const int bz = wg / (gx * gy);
  const int rr = wg - bz * gx * gy;
  const int by = rr / gx, bx = rr - by * gx;
  const int bm = by * 128, bn = bx * 128;

  // staging: slot q = w*2+i covers rows q*16+(lane>>2), chunk lane&3 (src-swz)
  const int r0 = (w * 2) * 16 + (lane >> 2);      // slot i=0 row
  const int csw = (((lane & 3) ^ (r0 & 3)) << 3); // elems; (r0+16)&3 == r0&3
  const ushort_t* pA0 = A + (long)bz * sA + (long)(bm + r0) * lda + csw;
  const ushort_t* pA1 = pA0 + 16 * lda;
  const ushort_t* pB0 = Bt + (long)bz * sB + (long)(bn + r0) * ldb + csw;
  const ushort_t* pB1 = pB0 + 16 * ldb;

  auto stage = [&](int kt, int buf) {
    const int k0 = kt << 5;
    ushort_t* s = sm + buf * 8192;
    gload16(pA0 + k0, s + (w * 2) * 512);
    gload16(pA1 + k0, s + (w * 2 + 1) * 512);
    gload16(pB0 + k0, s + 4096 + (w * 2) * 512);
    gload16(pB1 + k0, s + 4096 + (w * 2 + 1) * 512);
  };

  // fragment ds_read offsets (ushort units, exclude buf base)
  const int l31 = lane & 31, kh = lane >> 5;
  int offA[2][2], offB[2][2];
#pragma unroll
  for (int m = 0; m < 2; ++m) {
    const int row = wr * 64 + m * 32 + l31;
#pragma unroll
    for (int s = 0; s < 2; ++s)
      offA[m][s] = row * 32 + (((s * 2 + kh) ^ (row & 3)) << 3);
  }
#pragma unroll
  for (int n = 0; n < 2; ++n) {
    const int row = wc * 64 + n * 32 + l31;
#pragma unroll
    for (int s = 0; s < 2; ++s)
      offB[n][s] = 4096 + row * 32 + (((s * 2 + kh) ^ (row & 3)) << 3);
  }

  f32x16_t acc[2][2];
#pragma unroll
  for (int m = 0; m < 2; ++m)
#pragma unroll
    for (int n = 0; n < 2; ++n)
#pragma unroll
      for (int i = 0; i < 16; ++i) acc[m][n][i] = 0.f;

  stage(0, 0);
  __syncthreads();

#define LDX(off) __builtin_bit_cast(bf16x8_t, *(const uint4*)(sp + (off)))
  const int nt = K >> 5;
  for (int kt = 0; kt < nt; ++kt) {
    const int cur = kt & 1;
    if (kt + 1 < nt) stage(kt + 1, cur ^ 1);   // in flight across MFMAs
    const ushort_t* sp = sm + cur * 8192;
    bf16x8_t af[2][2], bf[2][2];
#pragma unroll
    for (int m = 0; m < 2; ++m)
#pragma unroll
      for (int s = 0; s < 2; ++s) af[m][s] = LDX(offA[m][s]);
#pragma unroll
    for (int n = 0; n < 2; ++n)
#pragma unroll
      for (int s = 0; s < 2; ++s) bf[n][s] = LDX(offB[n][s]);
#pragma unroll
    for (int s = 0; s < 2; ++s)
#pragma unroll
      for (int m = 0; m < 2; ++m)
#pragma unroll
        for (int n = 0; n < 2; ++n)
          acc[m][n] = __builtin_amdgcn_mfma_f32_32x32x16_bf16(
              af[m][s], bf[n][s], acc[m][n], 0, 0, 0);
    __syncthreads();
  }
#undef LDX

  // epilogue: C/D 32x32 layout: col=lane&31, row=(r&3)+8*(r>>2)+4*kh
  const long zC = (long)bz * sC;
#pragma unroll
  for (int m = 0; m < 2; ++m) {
    const int growb = bm + wr * 64 + m * 32;
#pragma unroll
    for (int n = 0; n < 2; ++n) {
      const int gcol = bn + wc * 64 + n * 32 + l31;
      float bv_ = 0.f;
      if constexpr (HAS_BIAS) bv_ = bias[gcol];
#pragma unroll
      for (int r = 0; r < 16; ++r) {
        const int grow = growb + (r & 3) + 8 * (r >> 2) + 4 * kh;
        const float v = acc[m][n][r] * alpha + bv_;
        if constexpr (OUT_BF16) {
          ((ushort_t*)Cp)[zC + (long)grow * ldc + gcol] = f2bf(v);
        } else {
          ((float*)Cp)[zC + (long)grow * ldc + gcol] = v;
        }
      }
    }
  }
}

// fp32 -> bf16 bulk convert for x and y in one launch (8 elems/thread)
__global__ __launch_bounds__(256)
void conv2(const float* __restrict__ x, const float* __restrict__ y,
           ushort_t* __restrict__ xb, ushort_t* __restrict__ yb) {
  const int b = blockIdx.x;
  const float* in = (b < 4096) ? x : y;
  ushort_t* out = (b < 4096) ? xb : yb;
  const long i = (long)(b & 4095) * 256 + threadIdx.x;
  const float4 a = ((const float4*)in)[i * 2];
  const float4 c = ((const float4*)in)[i * 2 + 1];
  uint4 o;
  o.x = (unsigned)f2bf(a.x) | ((unsigned)f2bf(a.y) << 16);
  o.y = (unsigned)f2bf(a.z) | ((unsigned)f2bf(a.w) << 16);
  o.z = (unsigned)f2bf(c.x) | ((unsigned)f2bf(c.y) << 16);
  o.w = (unsigned)f2bf(c.z) | ((unsigned)f2bf(c.w) << 16);
  ((uint4*)out)[i] = o;
}

// Wt[n][k] = (bf16) W[k][n], D=1024, 3 weights in one launch (z selects)
__global__ __launch_bounds__(256)
void wtrans3(const float* __restrict__ W0, const float* __restrict__ W1,
             const float* __restrict__ W2, ushort_t* __restrict__ T0,
             ushort_t* __restrict__ T1, ushort_t* __restrict__ T2) {
  const float* W = (blockIdx.z == 0) ? W0 : (blockIdx.z == 1) ? W1 : W2;
  ushort_t* Wt = (blockIdx.z == 0) ? T0 : (blockIdx.z == 1) ? T1 : T2;
  __shared__ float tile[32][33];
  const int bx = blockIdx.x * 32;
  const int by = blockIdx.y * 32;
  const int t = threadIdx.x;
  const int c = t & 31, r0 = t >> 5;
#pragma unroll
  for (int i = 0; i < 4; ++i)
    tile[r0 + i * 8][c] = W[(long)(by + r0 + i * 8) * 1024 + bx + c];
  __syncthreads();
#pragma unroll
  for (int i = 0; i < 4; ++i)
    Wt[(long)(bx + r0 + i * 8) * 1024 + by + c] = f2bf(tile[c][r0 + i * 8]);
}

__global__ __launch_bounds__(256)
void bconcat(const float* __restrict__ a, const float* __restrict__ b,
             float* __restrict__ o) {
  const int i = blockIdx.x * 256 + threadIdx.x;
  o[i] = (i < 1024) ? a[i] : b[i - 1024];
}

// bf16 transpose with strides: out[c][r] = in[r][c], 64x64 tiles per batch
__global__ __launch_bounds__(256)
void transpose_bf16(const ushort_t* __restrict__ in, ushort_t* __restrict__ out,
                    int ld_in, int ld_out, long in_bs, long out_bs) {
  __shared__ ushort_t tt[64][65];
  in += (long)blockIdx.z * in_bs;
  out += (long)blockIdx.z * out_bs;
  const int r0 = blockIdx.y * 64, c0 = blockIdx.x * 64;
  const int tc = threadIdx.x & 31;
  const int tr = threadIdx.x >> 5;
#pragma unroll
  for (int i = 0; i < 8; ++i) {
    const unsigned v = *(const unsigned*)(in + (long)(r0 + tr + 8 * i) * ld_in + c0 + tc * 2);
    tt[tr + 8 * i][tc * 2] = (ushort_t)(v & 0xffff);
    tt[tr + 8 * i][tc * 2 + 1] = (ushort_t)(v >> 16);
  }
  __syncthreads();
#pragma unroll
  for (int i = 0; i < 8; ++i) {
    const unsigned v = (unsigned)tt[tc * 2][tr + 8 * i] |
                       ((unsigned)tt[tc * 2 + 1][tr + 8 * i] << 16);
    *(unsigned*)(out + (long)(c0 + tr + 8 * i) * ld_out + r0 + tc * 2) = v;
  }
}

// In-place softmax over rows of S (bf16), 2048 cols, one block per row.
__global__ __launch_bounds__(256)
void softmax_rows(ushort_t* __restrict__ S) {
  const long row = blockIdx.x;
  ushort_t* p = S + row * 2048;
  const int t = threadIdx.x;
  uint4 v = ((uint4*)p)[t];
  ushort_t* hp = (ushort_t*)&v;
  float f[8];
#pragma unroll
  for (int j = 0; j < 8; ++j) f[j] = bf2f(hp[j]);

  float m = f[0];
#pragma unroll
  for (int j = 1; j < 8; ++j) m = fmaxf(m, f[j]);
#pragma unroll
  for (int s = 32; s; s >>= 1) m = fmaxf(m, __shfl_xor(m, s, 64));
  __shared__ float redm[4];
  __shared__ float reds[4];
  const int wave = t >> 6, lane = t & 63;
  if (lane == 0) redm[wave] = m;
  __syncthreads();
  m = fmaxf(fmaxf(redm[0], redm[1]), fmaxf(redm[2], redm[3]));

  float sum = 0.f;
#pragma unroll
  for (int j = 0; j < 8; ++j) { f[j] = __expf(f[j] - m); sum += f[j]; }
#pragma unroll
  for (int s = 32; s; s >>= 1) sum += __shfl_xor(sum, s, 64);
  if (lane == 0) reds[wave] = sum;
  __syncthreads();
  sum = reds[0] + reds[1] + reds[2] + reds[3];
  const float inv = 1.0f / sum;
#pragma unroll
  for (int j = 0; j < 8; ++j) hp[j] = f2bf(f[j] * inv);
  ((uint4*)p)[t] = v;
}

extern "C" void kernel_launch(void* const* d_in, const int* in_sizes, int n_in,
                              void* d_out, int out_size, void* d_ws, size_t ws_size,
                              hipStream_t stream) {
  const float* x  = (const float*)d_in[0];
  const float* y  = (const float*)d_in[1];
  const float* Wq = (const float*)d_in[2];
  const float* bq = (const float*)d_in[3];
  const float* Wk = (const float*)d_in[4];
  const float* bk = (const float*)d_in[5];
  const float* Wv = (const float*)d_in[6];
  const float* bv = (const float*)d_in[7];
  float* out = (float*)d_out;

  const int D = 1024;
  const long MB_ = 1l << 20;

  ushort_t* ws  = (ushort_t*)d_ws;
  ushort_t* Wqt = ws;                    // [1024][1024], 1M
  ushort_t* Wkv = ws + 1 * MB_;          // Wkt||Wvt = [2048][1024], 2M
  ushort_t* Wvt = ws + 2 * MB_;
  ushort_t* Qb  = ws + 3 * MB_;          // [8192][1024], 8M
  ushort_t* KV  = ws + 11 * MB_;         // [8192][2048], 16M
  ushort_t* yb  = ws + 27 * MB_;         // [8192][1024], 8M
  ushort_t* Vt  = ws + 27 * MB_;         // alias yb: [B][1024][2048]
  ushort_t* xb  = ws + 35 * MB_;         // [8192][1024], 8M
  ushort_t* Sb  = ws + 35 * MB_;         // alias xb: [B][2048][2048], 16M
  float*    bkv = (float*)(ws + 51 * MB_);  // [2048]

  dim3 blk(256);

  conv2<<<dim3(8192), blk, 0, stream>>>(x, y, xb, yb);
  wtrans3<<<dim3(32, 32, 3), blk, 0, stream>>>(Wq, Wk, Wv, Wqt, Wkv, Wvt);
  bconcat<<<dim3(8), blk, 0, stream>>>(bk, bv, bkv);

  // Q = xb @ Wqt^T + bq -> [8192][1024]; grid 8x64 = 512 (2 blocks/CU)
  gemm32<true, true><<<dim3(512), blk, 0, stream>>>(
      xb, Wqt, Qb, bq, 8, 64, D, D, D, D, 0, 0, 0, 1.0f);
  // KV = yb @ Wkv^T + bkv -> [8192][2048]; grid 16x64 = 1024 (4 blocks/CU)
  gemm32<true, true><<<dim3(1024), blk, 0, stream>>>(
      yb, Wkv, KV, bkv, 16, 64, D, D, D, 2048, 0, 0, 0, 1.0f);
  // Vt[b][d][t] = KV[b*2048+t][1024+d]
  transpose_bf16<<<dim3(16, 32, 4), blk, 0, stream>>>(
      KV + 1024, Vt, 2048, 2048, 2048l * 2048, 1024l * 2048);

  // S = (Q_b @ K_b^T)/32 -> bf16 [B][2048][2048]; grid 16x16x4 = 1024
  gemm32<true, false><<<dim3(1024), blk, 0, stream>>>(
      Qb, KV, Sb, nullptr, 16, 16, D, D, 2048, 2048,
      2048l * 1024, 2048l * 2048, 2048l * 2048, 0.03125f);

  softmax_rows<<<dim3(8192), blk, 0, stream>>>(Sb);

  // out = P_b @ V_b (NT vs Vt [1024][2048]) -> fp32; grid 8x16x4 = 512
  gemm32<false, false><<<dim3(512), blk, 0, stream>>>(
      Sb, Vt, out, nullptr, 8, 16, 2048, 2048, 2048, D,
      2048l * 2048, 1024l * 2048, 2048l * 1024, 1.0f);
}

// Round 7
// 212.684 us; speedup vs baseline: 1.0217x; 1.0217x over previous
//
#include <hip/hip_runtime.h>

typedef __bf16 bf16x8_t __attribute__((ext_vector_type(8)));
typedef float f32x16_t __attribute__((ext_vector_type(16)));
typedef unsigned short ushort_t;

__device__ __forceinline__ unsigned short f2bf(float f) {
  unsigned u = __float_as_uint(f);
  u = (u + 0x7FFFu + ((u >> 16) & 1u)) >> 16;
  return (unsigned short)u;
}
__device__ __forceinline__ float bf2f(unsigned short h) {
  return __uint_as_float(((unsigned)h) << 16);
}

// async global->LDS, 16B/lane. LDS dest = wave-uniform base + lane*16.
__device__ __forceinline__ void gload16(const void* g, void* l) {
  __builtin_amdgcn_global_load_lds(
      (const __attribute__((address_space(1))) unsigned int*)g,
      (__attribute__((address_space(3))) unsigned int*)l, 16, 0, 0);
}

// ===========================================================================
// 128x128 NT GEMM on mfma_f32_32x32x16_bf16. m97-proven loop: 1 __syncthreads
// per K-tile, gload_lds dbuf staging, 4 blocks/CU TLP hides barrier stalls.
// BK=32 (64B rows = 4 x 16B chunks).
// Swizzle g(row) = (row>>1)&3  [round-2 proven-zero-conflict pattern]:
//   LDS(row,chunk) = G(row, chunk ^ g(row)); ds_read XORs the same.
//   Slot = 16*(row&1) + 4*chunk: 8 consecutive rows -> 8 distinct 16B slots,
//   2 lanes/slot per 16-lane group = conflict-free (m136: 2-way free).
// 4 waves (2x2), wave = 64x64 out = 2x2 frags of 32x32, acc = 4 x f32x16.
// A/B frag: row=lane&31, k-half=lane>>5.  C/D: col=lane&31,
// row=(reg&3)+8*(reg>>2)+4*(lane>>5)  [m74/m101].
// ===========================================================================
template<bool OUT_BF16, bool HAS_BIAS>
__global__ __launch_bounds__(256, 4)
void gemm32(const ushort_t* __restrict__ A, const ushort_t* __restrict__ Bt,
            void* __restrict__ Cp, const float* __restrict__ bias,
            int gx, int gy, int K, int lda, int ldb, int ldc,
            long sA, long sB, long sC, float alpha)
{
  __shared__ __align__(16) ushort_t sm[16384];  // 2 buf x (A 4096 + B 4096)
  const int tid = threadIdx.x;
  const int lane = tid & 63;
  const int w = tid >> 6;                 // wave 0..3
  const int wr = w >> 1, wc = w & 1;

  // bijective XCD-chunked swizzle (all grids %8==0)
  const int per = gridDim.x >> 3;
  int wg = blockIdx.x;
  wg = (wg & 7) * per + (wg >> 3);
  const int bz = wg / (gx * gy);
  const int rr = wg - bz * gx * gy;
  const int by = rr / gx, bx = rr - by * gx;
  const int bm = by * 128, bn = bx * 128;

  // staging: slot q = w*2+i covers rows q*16+(lane>>2), chunk lane&3 (src-swz)
  // g(row) = (row>>1)&3 is invariant under row+16, so both slots share csw.
  const int r0 = (w * 2) * 16 + (lane >> 2);          // slot i=0 row
  const int csw = (((lane & 3) ^ ((r0 >> 1) & 3)) << 3);  // elems
  const ushort_t* pA0 = A + (long)bz * sA + (long)(bm + r0) * lda + csw;
  const ushort_t* pA1 = pA0 + 16 * lda;
  const ushort_t* pB0 = Bt + (long)bz * sB + (long)(bn + r0) * ldb + csw;
  const ushort_t* pB1 = pB0 + 16 * ldb;

  auto stage = [&](int kt, int buf) {
    const int k0 = kt << 5;
    ushort_t* s = sm + buf * 8192;
    gload16(pA0 + k0, s + (w * 2) * 512);
    gload16(pA1 + k0, s + (w * 2 + 1) * 512);
    gload16(pB0 + k0, s + 4096 + (w * 2) * 512);
    gload16(pB1 + k0, s + 4096 + (w * 2 + 1) * 512);
  };

  // fragment ds_read offsets (ushort units, exclude buf base)
  const int l31 = lane & 31, kh = lane >> 5;
  int offA[2][2], offB[2][2];
#pragma unroll
  for (int m = 0; m < 2; ++m) {
    const int row = wr * 64 + m * 32 + l31;
#pragma unroll
    for (int s = 0; s < 2; ++s)
      offA[m][s] = row * 32 + (((s * 2 + kh) ^ ((row >> 1) & 3)) << 3);
  }
#pragma unroll
  for (int n = 0; n < 2; ++n) {
    const int row = wc * 64 + n * 32 + l31;
#pragma unroll
    for (int s = 0; s < 2; ++s)
      offB[n][s] = 4096 + row * 32 + (((s * 2 + kh) ^ ((row >> 1) & 3)) << 3);
  }

  f32x16_t acc[2][2];
#pragma unroll
  for (int m = 0; m < 2; ++m)
#pragma unroll
    for (int n = 0; n < 2; ++n)
#pragma unroll
      for (int i = 0; i < 16; ++i) acc[m][n][i] = 0.f;

  stage(0, 0);
  __syncthreads();

#define LDX(off) __builtin_bit_cast(bf16x8_t, *(const uint4*)(sp + (off)))
  const int nt = K >> 5;
  for (int kt = 0; kt < nt; ++kt) {
    const int cur = kt & 1;
    if (kt + 1 < nt) stage(kt + 1, cur ^ 1);   // in flight across MFMAs
    const ushort_t* sp = sm + cur * 8192;
    bf16x8_t af[2][2], bf[2][2];
#pragma unroll
    for (int m = 0; m < 2; ++m)
#pragma unroll
      for (int s = 0; s < 2; ++s) af[m][s] = LDX(offA[m][s]);
#pragma unroll
    for (int n = 0; n < 2; ++n)
#pragma unroll
      for (int s = 0; s < 2; ++s) bf[n][s] = LDX(offB[n][s]);
#pragma unroll
    for (int s = 0; s < 2; ++s)
#pragma unroll
      for (int m = 0; m < 2; ++m)
#pragma unroll
        for (int n = 0; n < 2; ++n)
          acc[m][n] = __builtin_amdgcn_mfma_f32_32x32x16_bf16(
              af[m][s], bf[n][s], acc[m][n], 0, 0, 0);
    __syncthreads();
  }
#undef LDX

  // epilogue: C/D 32x32 layout: col=lane&31, row=(r&3)+8*(r>>2)+4*kh
  const long zC = (long)bz * sC;
#pragma unroll
  for (int m = 0; m < 2; ++m) {
    const int growb = bm + wr * 64 + m * 32;
#pragma unroll
    for (int n = 0; n < 2; ++n) {
      const int gcol = bn + wc * 64 + n * 32 + l31;
      float bv_ = 0.f;
      if constexpr (HAS_BIAS) bv_ = bias[gcol];
#pragma unroll
      for (int r = 0; r < 16; ++r) {
        const int grow = growb + (r & 3) + 8 * (r >> 2) + 4 * kh;
        const float v = acc[m][n][r] * alpha + bv_;
        if constexpr (OUT_BF16) {
          ((ushort_t*)Cp)[zC + (long)grow * ldc + gcol] = f2bf(v);
        } else {
          ((float*)Cp)[zC + (long)grow * ldc + gcol] = v;
        }
      }
    }
  }
}

// fp32 -> bf16 bulk convert for x and y in one launch (8 elems/thread)
__global__ __launch_bounds__(256)
void conv2(const float* __restrict__ x, const float* __restrict__ y,
           ushort_t* __restrict__ xb, ushort_t* __restrict__ yb) {
  const int b = blockIdx.x;
  const float* in = (b < 4096) ? x : y;
  ushort_t* out = (b < 4096) ? xb : yb;
  const long i = (long)(b & 4095) * 256 + threadIdx.x;
  const float4 a = ((const float4*)in)[i * 2];
  const float4 c = ((const float4*)in)[i * 2 + 1];
  uint4 o;
  o.x = (unsigned)f2bf(a.x) | ((unsigned)f2bf(a.y) << 16);
  o.y = (unsigned)f2bf(a.z) | ((unsigned)f2bf(a.w) << 16);
  o.z = (unsigned)f2bf(c.x) | ((unsigned)f2bf(c.y) << 16);
  o.w = (unsigned)f2bf(c.z) | ((unsigned)f2bf(c.w) << 16);
  ((uint4*)out)[i] = o;
}

// Wt[n][k] = (bf16) W[k][n], D=1024, 3 weights in one launch (z selects)
__global__ __launch_bounds__(256)
void wtrans3(const float* __restrict__ W0, const float* __restrict__ W1,
             const float* __restrict__ W2, ushort_t* __restrict__ T0,
             ushort_t* __restrict__ T1, ushort_t* __restrict__ T2) {
  const float* W = (blockIdx.z == 0) ? W0 : (blockIdx.z == 1) ? W1 : W2;
  ushort_t* Wt = (blockIdx.z == 0) ? T0 : (blockIdx.z == 1) ? T1 : T2;
  __shared__ float tile[32][33];
  const int bx = blockIdx.x * 32;
  const int by = blockIdx.y * 32;
  const int t = threadIdx.x;
  const int c = t & 31, r0 = t >> 5;
#pragma unroll
  for (int i = 0; i < 4; ++i)
    tile[r0 + i * 8][c] = W[(long)(by + r0 + i * 8) * 1024 + bx + c];
  __syncthreads();
#pragma unroll
  for (int i = 0; i < 4; ++i)
    Wt[(long)(bx + r0 + i * 8) * 1024 + by + c] = f2bf(tile[c][r0 + i * 8]);
}

__global__ __launch_bounds__(256)
void bconcat(const float* __restrict__ a, const float* __restrict__ b,
             float* __restrict__ o) {
  const int i = blockIdx.x * 256 + threadIdx.x;
  o[i] = (i < 1024) ? a[i] : b[i - 1024];
}

// bf16 transpose with strides: out[c][r] = in[r][c], 64x64 tiles per batch
__global__ __launch_bounds__(256)
void transpose_bf16(const ushort_t* __restrict__ in, ushort_t* __restrict__ out,
                    int ld_in, int ld_out, long in_bs, long out_bs) {
  __shared__ ushort_t tt[64][65];
  in += (long)blockIdx.z * in_bs;
  out += (long)blockIdx.z * out_bs;
  const int r0 = blockIdx.y * 64, c0 = blockIdx.x * 64;
  const int tc = threadIdx.x & 31;
  const int tr = threadIdx.x >> 5;
#pragma unroll
  for (int i = 0; i < 8; ++i) {
    const unsigned v = *(const unsigned*)(in + (long)(r0 + tr + 8 * i) * ld_in + c0 + tc * 2);
    tt[tr + 8 * i][tc * 2] = (ushort_t)(v & 0xffff);
    tt[tr + 8 * i][tc * 2 + 1] = (ushort_t)(v >> 16);
  }
  __syncthreads();
#pragma unroll
  for (int i = 0; i < 8; ++i) {
    const unsigned v = (unsigned)tt[tc * 2][tr + 8 * i] |
                       ((unsigned)tt[tc * 2 + 1][tr + 8 * i] << 16);
    *(unsigned*)(out + (long)(c0 + tr + 8 * i) * ld_out + r0 + tc * 2) = v;
  }
}

// In-place softmax over rows of S (bf16), 2048 cols, one block per row.
__global__ __launch_bounds__(256)
void softmax_rows(ushort_t* __restrict__ S) {
  const long row = blockIdx.x;
  ushort_t* p = S + row * 2048;
  const int t = threadIdx.x;
  uint4 v = ((uint4*)p)[t];
  ushort_t* hp = (ushort_t*)&v;
  float f[8];
#pragma unroll
  for (int j = 0; j < 8; ++j) f[j] = bf2f(hp[j]);

  float m = f[0];
#pragma unroll
  for (int j = 1; j < 8; ++j) m = fmaxf(m, f[j]);
#pragma unroll
  for (int s = 32; s; s >>= 1) m = fmaxf(m, __shfl_xor(m, s, 64));
  __shared__ float redm[4];
  __shared__ float reds[4];
  const int wave = t >> 6, lane = t & 63;
  if (lane == 0) redm[wave] = m;
  __syncthreads();
  m = fmaxf(fmaxf(redm[0], redm[1]), fmaxf(redm[2], redm[3]));

  float sum = 0.f;
#pragma unroll
  for (int j = 0; j < 8; ++j) { f[j] = __expf(f[j] - m); sum += f[j]; }
#pragma unroll
  for (int s = 32; s; s >>= 1) sum += __shfl_xor(sum, s, 64);
  if (lane == 0) reds[wave] = sum;
  __syncthreads();
  sum = reds[0] + reds[1] + reds[2] + reds[3];
  const float inv = 1.0f / sum;
#pragma unroll
  for (int j = 0; j < 8; ++j) hp[j] = f2bf(f[j] * inv);
  ((uint4*)p)[t] = v;
}

extern "C" void kernel_launch(void* const* d_in, const int* in_sizes, int n_in,
                              void* d_out, int out_size, void* d_ws, size_t ws_size,
                              hipStream_t stream) {
  const float* x  = (const float*)d_in[0];
  const float* y  = (const float*)d_in[1];
  const float* Wq = (const float*)d_in[2];
  const float* bq = (const float*)d_in[3];
  const float* Wk = (const float*)d_in[4];
  const float* bk = (const float*)d_in[5];
  const float* Wv = (const float*)d_in[6];
  const float* bv = (const float*)d_in[7];
  float* out = (float*)d_out;

  const int D = 1024;
  const long MB_ = 1l << 20;

  ushort_t* ws  = (ushort_t*)d_ws;
  ushort_t* Wqt = ws;                    // [1024][1024], 1M
  ushort_t* Wkv = ws + 1 * MB_;          // Wkt||Wvt = [2048][1024], 2M
  ushort_t* Wvt = ws + 2 * MB_;
  ushort_t* Qb  = ws + 3 * MB_;          // [8192][1024], 8M
  ushort_t* KV  = ws + 11 * MB_;         // [8192][2048], 16M
  ushort_t* yb  = ws + 27 * MB_;         // [8192][1024], 8M
  ushort_t* Vt  = ws + 27 * MB_;         // alias yb: [B][1024][2048]
  ushort_t* xb  = ws + 35 * MB_;         // [8192][1024], 8M
  ushort_t* Sb  = ws + 35 * MB_;         // alias xb: [B][2048][2048], 16M
  float*    bkv = (float*)(ws + 51 * MB_);  // [2048]

  dim3 blk(256);

  conv2<<<dim3(8192), blk, 0, stream>>>(x, y, xb, yb);
  wtrans3<<<dim3(32, 32, 3), blk, 0, stream>>>(Wq, Wk, Wv, Wqt, Wkv, Wvt);
  bconcat<<<dim3(8), blk, 0, stream>>>(bk, bv, bkv);

  // Q = xb @ Wqt^T + bq -> [8192][1024]; grid 8x64 = 512 (2 blocks/CU)
  gemm32<true, true><<<dim3(512), blk, 0, stream>>>(
      xb, Wqt, Qb, bq, 8, 64, D, D, D, D, 0, 0, 0, 1.0f);
  // KV = yb @ Wkv^T + bkv -> [8192][2048]; grid 16x64 = 1024 (4 blocks/CU)
  gemm32<true, true><<<dim3(1024), blk, 0, stream>>>(
      yb, Wkv, KV, bkv, 16, 64, D, D, D, 2048, 0, 0, 0, 1.0f);
  // Vt[b][d][t] = KV[b*2048+t][1024+d]
  transpose_bf16<<<dim3(16, 32, 4), blk, 0, stream>>>(
      KV + 1024, Vt, 2048, 2048, 2048l * 2048, 1024l * 2048);

  // S = (Q_b @ K_b^T)/32 -> bf16 [B][2048][2048]; grid 16x16x4 = 1024
  gemm32<true, false><<<dim3(1024), blk, 0, stream>>>(
      Qb, KV, Sb, nullptr, 16, 16, D, D, 2048, 2048,
      2048l * 1024, 2048l * 2048, 2048l * 2048, 0.03125f);

  softmax_rows<<<dim3(8192), blk, 0, stream>>>(Sb);

  // out = P_b @ V_b (NT vs Vt [1024][2048]) -> fp32; grid 8x16x4 = 512
  gemm32<false, false><<<dim3(512), blk, 0, stream>>>(
      Sb, Vt, out, nullptr, 8, 16, 2048, 2048, 2048, D,
      2048l * 2048, 1024l * 2048, 2048l * 1024, 1.0f);
}